// Round 17
// baseline (309.712 us; speedup 1.0000x reference)
//
#include <hip/hip_runtime.h>

typedef unsigned short u16;
typedef __attribute__((ext_vector_type(8))) short bf16x8;
typedef __attribute__((ext_vector_type(4))) short bf16x4;
typedef __attribute__((ext_vector_type(4))) float f32x4;

#define TP 28
#define NB 4096
#define L2E 1.4426950408889634f

__device__ __forceinline__ u16 f2bf(float x) {
  union { float f; unsigned u; } v; v.f = x;
  unsigned u = v.u;
  return (u16)((u + 0x7fffu + ((u >> 16) & 1u)) >> 16);
}
__device__ __forceinline__ float rcp_(float x) {
  float r;
  asm("v_rcp_f32 %0, %1" : "=v"(r) : "v"(x));
  return r;
}
__device__ __forceinline__ float exp2_(float x) {
  float r;
  asm("v_exp_f32 %0, %1" : "=v"(r) : "v"(x));
  return r;
}
__device__ __forceinline__ float sigm2(float x) { return rcp_(1.0f + exp2_(-x)); }
__device__ __forceinline__ float tanh2(float x) { return 1.0f - 2.0f * rcp_(1.0f + exp2_(x)); }
__device__ __forceinline__ float sigm(float x) { return rcp_(1.0f + __expf(-x)); }
__device__ __forceinline__ float leaky(float x) { return x >= 0.0f ? x : 0.1f * x; }
__device__ __forceinline__ f32x4 mfma16(bf16x8 a, bf16x8 b, f32x4 c) {
  return __builtin_amdgcn_mfma_f32_16x16x32_bf16(a, b, c, 0, 0, 0);
}
__device__ __forceinline__ bf16x8 pack8s(float4 a, float4 b, float s) {
  bf16x8 f;
  f[0] = (short)f2bf(a.x * s); f[1] = (short)f2bf(a.y * s);
  f[2] = (short)f2bf(a.z * s); f[3] = (short)f2bf(a.w * s);
  f[4] = (short)f2bf(b.x * s); f[5] = (short)f2bf(b.y * s);
  f[6] = (short)f2bf(b.z * s); f[7] = (short)f2bf(b.w * s);
  return f;
}
__device__ __forceinline__ bf16x8 ldfrag8s(const float* p, float s) {
  float4 u0 = *(const float4*)p;
  float4 u1 = *(const float4*)(p + 4);
  return pack8s(u0, u1, s);
}

// ---------------- conv1 (R16 wave-independent) + fused BN1-stats tail ----------------
__global__ __launch_bounds__(512, 4) void k_conv1(
    const float* __restrict__ poses, const float* __restrict__ w1,
    const float* __restrict__ b1, const float* __restrict__ bn1g,
    const float* __restrict__ bn1b, float* __restrict__ y1,
    float* __restrict__ p1, float* __restrict__ sc,
    unsigned* __restrict__ cnt)
{
  __shared__ __align__(16) u16 xw[8][3264];   // per-wave window (3240 + pad)
  __shared__ __align__(16) u16 wt[16][544];   // [co][k], k = tap*180+ci; k>=540 zero
  __shared__ float sp[8][16];
  __shared__ float sq[8][16];
  __shared__ float redl[16][32];
  __shared__ float totl[32];
  __shared__ int lastFlag;
  const int tid = threadIdx.x;
  const int lane = tid & 63;
  const int wv = tid >> 6;

  if (tid < 64) wt[tid >> 2][540 + (tid & 3)] = 0;
  for (int i = tid; i < 8640; i += 512) {
    int co_ = i / 540, r = i % 540, ci = r / 3, tap = r % 3;
    wt[co_][tap * 180 + ci] = f2bf(w1[i]);
  }
  __syncthreads();

  const int b0 = blockIdx.x * 4;
  const int bb = wv >> 1;
  const int b = b0 + bb;
  const int t0 = (wv & 1) * 16;
  {
    const float4* src = (const float4*)(poses + (size_t)b * 6120 + t0 * 180);
    u16* dst = xw[wv];
    if (lane < 24) dst[3240 + lane] = 0;
#pragma unroll
    for (int j = 0; j < 13; ++j) {
      const int idx = j * 64 + lane;
      if (idx < 810) {
        float4 v = src[idx];
        unsigned lo = (unsigned)f2bf(v.x) | ((unsigned)f2bf(v.y) << 16);
        unsigned hi = (unsigned)f2bf(v.z) | ((unsigned)f2bf(v.w) << 16);
        *(uint2*)&dst[idx * 4] = make_uint2(lo, hi);
      }
    }
  }

  const int co = lane & 15;
  const int kgrp = lane >> 4;
  const int kg = kgrp * 8;
  const int R0 = kgrp * 4;
  const u16* pr = &xw[wv][co * 180];
  const float bias = b1[co];
  f32x4 acc = {bias, bias, bias, bias};

#pragma unroll
  for (int s = 0; s < 17; ++s) {
    bf16x4 lo = *(const bf16x4*)(pr + s * 32 + kg);
    bf16x4 hi = *(const bf16x4*)(pr + s * 32 + kg + 4);
    bf16x8 a0 = {lo[0], lo[1], lo[2], lo[3], hi[0], hi[1], hi[2], hi[3]};
    bf16x8 wf = *(const bf16x8*)&wt[co][s * 32 + kg];
    acc = mfma16(a0, wf, acc);
  }

  float s_ = 0.f, q_ = 0.f;
#pragma unroll
  for (int r = 0; r < 4; ++r) { s_ += acc[r]; q_ += acc[r] * acc[r]; }
  *(float4*)(y1 + (size_t)b * 512 + co * 32 + t0 + R0) =
      make_float4(acc[0], acc[1], acc[2], acc[3]);
  s_ += __shfl_xor(s_, 16); q_ += __shfl_xor(q_, 16);
  s_ += __shfl_xor(s_, 32); q_ += __shfl_xor(q_, 32);
  if (lane < 16) { sp[wv][co] = s_; sq[wv][co] = q_; }
  __syncthreads();
  if (tid < 32) {
    int ss = tid >> 4, c = tid & 15;
    float v = 0.f;
#pragma unroll
    for (int w2 = 0; w2 < 8; ++w2) v += ss ? sq[w2][c] : sp[w2][c];
    p1[blockIdx.x * 32 + ss * 16 + c] = v;
  }
  // ---- last-block BN1 stats (threadfence reduction) ----
  __threadfence();
  __syncthreads();
  if (tid == 0) lastFlag = (atomicAdd(cnt, 1u) == 1023u) ? 1 : 0;
  __syncthreads();
  if (lastFlag) {
    __threadfence();
    const int col = tid & 31, rg = tid >> 5;  // 16 groups x 32 cols
    float a = 0;
    for (int r = rg; r < 1024; r += 16) a += p1[r * 32 + col];
    redl[rg][col] = a;
    __syncthreads();
    if (tid < 32) {
      float t = 0;
#pragma unroll
      for (int i = 0; i < 16; ++i) t += redl[i][tid];
      totl[tid] = t;
    }
    __syncthreads();
    if (tid < 16) {
      const float inv = 1.0f / 131072.0f;
      float m = totl[tid] * inv;
      float var = totl[16 + tid] * inv - m * m;
      float s = bn1g[tid] * rsqrtf(fmaxf(var, 0.0f) + 1e-5f);
      sc[tid] = s;
      sc[16 + tid] = bn1b[tid] - m * s;
    }
  }
}

// -------- conv2 + fused BN2-stats tail: bn1+leaky(y1) -> y2 + sc2 --------
__global__ __launch_bounds__(256) void k_conv2(
    const float* __restrict__ y1, const float* __restrict__ sc,
    const float* __restrict__ w2, const float* __restrict__ b2,
    const float* __restrict__ bn2g, const float* __restrict__ bn2b,
    float* __restrict__ y2, float* __restrict__ p2,
    float* __restrict__ scw, unsigned* __restrict__ cnt)
{
  __shared__ float a1[8][16][33];
  __shared__ float w2s[384];
  __shared__ float sp[4][8][2];
  __shared__ float redl[16][16];
  __shared__ float totl[16];
  __shared__ int lastFlag;
  const int tid = threadIdx.x;
  const int b0 = blockIdx.x * 8;
  for (int i = tid; i < 384; i += 256) w2s[i] = w2[i];
  for (int i = tid; i < 4096; i += 256) {
    int bb = i >> 9, c = (i >> 5) & 15, t = i & 31;
    float v = y1[(size_t)(b0 + bb) * 512 + c * 32 + t] * sc[c] + sc[16 + c];
    a1[bb][c][t] = leaky(v);
  }
  __syncthreads();
  float acc[8];
  const int bb = tid / 30, t = tid % 30;
  const bool act = tid < 240;
#pragma unroll
  for (int co = 0; co < 8; ++co) acc[co] = act ? b2[co] : 0.0f;
  if (act) {
    for (int ci = 0; ci < 16; ++ci) {
      float x0 = a1[bb][ci][t], x1 = a1[bb][ci][t + 1], x2 = a1[bb][ci][t + 2];
#pragma unroll
      for (int co = 0; co < 8; ++co) {
        const float* wp = &w2s[co * 48 + ci * 3];
        acc[co] += x0 * wp[0] + x1 * wp[1] + x2 * wp[2];
      }
    }
    for (int co = 0; co < 8; ++co)
      y2[(size_t)(b0 + bb) * 240 + co * 30 + t] = acc[co];
  }
  const int w = tid >> 6;
#pragma unroll
  for (int co = 0; co < 8; ++co) {
    float s = act ? acc[co] : 0.0f;
    float q = s * s;
#pragma unroll
    for (int m = 1; m <= 32; m <<= 1) { s += __shfl_xor(s, m); q += __shfl_xor(q, m); }
    if ((tid & 63) == 0) { sp[w][co][0] = s; sp[w][co][1] = q; }
  }
  __syncthreads();
  if (tid < 16) {
    int s = tid >> 3, c = tid & 7;
    p2[blockIdx.x * 16 + s * 8 + c] = sp[0][c][s] + sp[1][c][s] + sp[2][c][s] + sp[3][c][s];
  }
  // ---- last-block BN2 stats ----
  __threadfence();
  __syncthreads();
  if (tid == 0) lastFlag = (atomicAdd(cnt, 1u) == 511u) ? 1 : 0;
  __syncthreads();
  if (lastFlag) {
    __threadfence();
    const int col = tid & 15, rg = tid >> 4;  // 16 groups x 16 cols
    float a = 0;
    for (int r = rg; r < 512; r += 16) a += p2[r * 16 + col];
    redl[rg][col] = a;
    __syncthreads();
    if (tid < 16) {
      float tt = 0;
#pragma unroll
      for (int i = 0; i < 16; ++i) tt += redl[i][tid];
      totl[tid] = tt;
    }
    __syncthreads();
    if (tid < 8) {
      const float inv = 1.0f / 122880.0f;
      float m = totl[tid] * inv;
      float var = totl[8 + tid] * inv - m * m;
      float s = bn2g[tid] * rsqrtf(fmaxf(var, 0.0f) + 1e-5f);
      scw[32 + tid] = s;
      scw[40 + tid] = bn2b[tid] - m * s;
    }
  }
}

// -------- gru: conv3 prologue (per-block 16 batches -> LDS featl) + 4-layer pipe + head --------
__global__ __launch_bounds__(1024) void k_gru_pipe(
    const float* __restrict__ y2, const float* __restrict__ sc,
    const float* __restrict__ w3, const float* __restrict__ b3,
    const float* __restrict__ g0wih,   // [192][8]
    const float* __restrict__ gwih,    // [3][192][64]
    const float* __restrict__ gwhh,    // [4][192][64]
    const float* __restrict__ gbih,    // [4][192]
    const float* __restrict__ gbhh,    // [4][192]
    const float* __restrict__ ow, const float* __restrict__ ob,
    const float* __restrict__ o2w, const float* __restrict__ o2b,
    float* __restrict__ out)
{
  __shared__ __align__(16) u16 featl[TP][16][40];  // cols 8..39 zero (K padding)
  __shared__ __align__(16) u16 hl[4][2][16][72];
  __shared__ float a2[16][8][31];
  __shared__ float w3s[192];
  __shared__ float sph[4][16];
  const int tid = threadIdx.x;
  const int b0 = blockIdx.x * 16;
  const int lane = tid & 63;
  const int wv = tid >> 6;        // 0..15
  const int l = wv >> 2;          // layer 0..3
  const int c = wv & 3;           // col-group 0..3
  const int row = lane & 15;
  const int kgrp = lane >> 4;
  const int kg = kgrp * 8;
  const int R0 = kgrp * 4;
  const int cr = c * 16 + row;    // gate column 0..63

  // prologue stage A: zero hl+featl, load w3s, stage bn2+leaky(y2) into a2
  for (int i = tid; i < 4 * 2 * 16 * 72; i += 1024) ((u16*)hl)[i] = 0;
  for (int i = tid; i < TP * 16 * 40; i += 1024) ((u16*)featl)[i] = 0;
  for (int i = tid; i < 192; i += 1024) w3s[i] = w3[i];
  for (int i = tid; i < 3840; i += 1024) {
    int bb = i / 240, rem = i % 240, cc = rem / 30, tt = rem % 30;
    float v = y2[(size_t)(b0 + bb) * 240 + cc * 30 + tt] * sc[32 + cc] + sc[40 + cc];
    a2[bb][cc][tt] = leaky(v);
  }

  // weight fragments (registers, independent of LDS)
  bf16x8 Wx[3][2], Wh[3][2];
  if (l == 0) {
#pragma unroll
    for (int g = 0; g < 3; ++g) {
      const float sc_ = (g == 2) ? 2.f * L2E : L2E;
      bf16x8 z;
#pragma unroll
      for (int j = 0; j < 8; ++j) z[j] = 0;
      if (kg == 0) z = ldfrag8s(g0wih + (g * 64 + cr) * 8, sc_);
      Wx[g][0] = z;
      Wx[g][1] = z;
    }
  } else {
#pragma unroll
    for (int g = 0; g < 3; ++g) {
      const float sc_ = (g == 2) ? 2.f * L2E : L2E;
#pragma unroll
      for (int s = 0; s < 2; ++s)
        Wx[g][s] = ldfrag8s(gwih + (l - 1) * 12288 + (g * 64 + cr) * 64 + s * 32 + kg, sc_);
    }
  }
#pragma unroll
  for (int g = 0; g < 3; ++g) {
    const float sc_ = (g == 2) ? 2.f * L2E : L2E;
#pragma unroll
    for (int s = 0; s < 2; ++s)
      Wh[g][s] = ldfrag8s(gwhh + l * 12288 + (g * 64 + cr) * 64 + s * 32 + kg, sc_);
  }

  const float br = (gbih[l * 192 + cr] + gbhh[l * 192 + cr]) * L2E;
  const float bz = (gbih[l * 192 + 64 + cr] + gbhh[l * 192 + 64 + cr]) * L2E;
  const float bi = gbih[l * 192 + 128 + cr] * 2.f * L2E;
  const float bh = gbhh[l * 192 + 128 + cr] * 2.f * L2E;

  __syncthreads();   // stage A complete (zeros + a2)

  // prologue stage B: conv3 -> featl cols 0..7
  if (tid < 448) {
    int bb = tid / 28, t = tid % 28;
    float accc[8];
#pragma unroll
    for (int co = 0; co < 8; ++co) accc[co] = b3[co];
    for (int ci = 0; ci < 8; ++ci) {
      float x0 = a2[bb][ci][t], x1 = a2[bb][ci][t + 1], x2 = a2[bb][ci][t + 2];
#pragma unroll
      for (int co = 0; co < 8; ++co) {
        const float* wp = &w3s[co * 24 + ci * 3];
        accc[co] += x0 * wp[0] + x1 * wp[1] + x2 * wp[2];
      }
    }
    union { u16 h[8]; uint4 v; } u;
#pragma unroll
    for (int co = 0; co < 8; ++co) u.h[co] = f2bf(accc[co]);
    *(uint4*)&featl[t][bb][0] = u.v;
  }
  __syncthreads();   // featl ready

  float hold[4] = {0.f, 0.f, 0.f, 0.f};
  float accL[4] = {0.f, 0.f, 0.f, 0.f};
  const float owv = ow[cr];

  for (int tick = 0; tick < TP + 3; ++tick) {
    const int t = tick - l;
    if (t >= 0 && t < TP) {
      const int cur = t & 1, nxt = cur ^ 1;
      bf16x8 ax0, ax1, ah0, ah1;
      if (l == 0) {
        ax0 = *(const bf16x8*)&featl[t][row][kg];
      } else {
        ax0 = *(const bf16x8*)&hl[l - 1][nxt][row][kg];      // h_{l-1}[t]
        ax1 = *(const bf16x8*)&hl[l - 1][nxt][row][32 + kg];
      }
      ah0 = *(const bf16x8*)&hl[l][cur][row][kg];            // h_l[t-1]
      ah1 = *(const bf16x8*)&hl[l][cur][row][32 + kg];

      f32x4 ar = {br, br, br, br};
      f32x4 az = {bz, bz, bz, bz};
      f32x4 ai = {bi, bi, bi, bi};
      f32x4 an = {bh, bh, bh, bh};

      __builtin_amdgcn_s_setprio(1);
      ar = mfma16(ax0, Wx[0][0], ar);
      az = mfma16(ax0, Wx[1][0], az);
      ai = mfma16(ax0, Wx[2][0], ai);
      if (l != 0) {
        ar = mfma16(ax1, Wx[0][1], ar);
        az = mfma16(ax1, Wx[1][1], az);
        ai = mfma16(ax1, Wx[2][1], ai);
      }
      ar = mfma16(ah0, Wh[0][0], ar);
      ar = mfma16(ah1, Wh[0][1], ar);
      az = mfma16(ah0, Wh[1][0], az);
      az = mfma16(ah1, Wh[1][1], az);
      an = mfma16(ah0, Wh[2][0], an);
      an = mfma16(ah1, Wh[2][1], an);
      __builtin_amdgcn_s_setprio(0);

      float o2 = 0.f;
      if (l == 3) o2 = o2w[t];
      u16 hb[4];
#pragma unroll
      for (int r = 0; r < 4; ++r) {
        float rr = sigm2(ar[r]);
        float zz = sigm2(az[r]);
        float nn = tanh2(ai[r] + rr * an[r]);
        float hv = nn + zz * (hold[r] - nn);
        hold[r] = hv;
        hb[r] = f2bf(hv);
        if (l == 3) accL[r] += hv * owv * o2;
      }
#pragma unroll
      for (int r = 0; r < 4; ++r) hl[l][nxt][R0 + r][cr] = hb[r];
    }
    __syncthreads();
  }

  if (l == 3) {
#pragma unroll
    for (int r = 0; r < 4; ++r) {
      accL[r] += __shfl_xor(accL[r], 1);
      accL[r] += __shfl_xor(accL[r], 2);
      accL[r] += __shfl_xor(accL[r], 4);
      accL[r] += __shfl_xor(accL[r], 8);
    }
    if ((lane & 15) == 0) {
#pragma unroll
      for (int r = 0; r < 4; ++r) sph[c][R0 + r] = accL[r];
    }
  }
  __syncthreads();
  if (tid < 16) {
    float s = sph[0][tid] + sph[1][tid] + sph[2][tid] + sph[3][tid];
    float so2 = 0.f;
    for (int t = 0; t < TP; ++t) so2 += o2w[t];
    out[b0 + tid] = sigm(s + ob[0] * so2 + o2b[0]);
  }
}

extern "C" void kernel_launch(void* const* d_in, const int* in_sizes, int n_in,
                              void* d_out, int out_size, void* d_ws, size_t ws_size,
                              hipStream_t stream)
{
  const float* poses = (const float*)d_in[0];
  const float* c1w = (const float*)d_in[1];
  const float* c1b = (const float*)d_in[2];
  const float* bn1g = (const float*)d_in[3];
  const float* bn1b = (const float*)d_in[4];
  const float* c2w = (const float*)d_in[5];
  const float* c2b = (const float*)d_in[6];
  const float* bn2g = (const float*)d_in[7];
  const float* bn2b = (const float*)d_in[8];
  const float* c3w = (const float*)d_in[9];
  const float* c3b = (const float*)d_in[10];
  const float* g0wih = (const float*)d_in[11];  // [192][8]
  const float* gwih = (const float*)d_in[12];   // [3][192][64]
  const float* gwhh = (const float*)d_in[13];   // [4][192][64]
  const float* gbih = (const float*)d_in[14];   // [4][192]
  const float* gbhh = (const float*)d_in[15];   // [4][192]
  const float* ow = (const float*)d_in[16];
  const float* ob = (const float*)d_in[17];
  const float* o2w = (const float*)d_in[18];
  const float* o2b = (const float*)d_in[19];

  float* ws = (float*)d_ws;
  float* y1 = ws;                         // 2,097,152 f32
  float* y2 = ws + 2097152;               //   983,040 f32
  float* p1 = ws + 3080192;               //    32,768 f32 (1024 x 32)
  float* p2 = ws + 3112960;               //     8,192 f32 (512 x 16)
  float* sc = ws + 3121152;               //        48 f32
  unsigned* cnt = (unsigned*)(ws + 3121200);  // 2 counters
  float* outv = (float*)d_out;

  hipMemsetAsync(cnt, 0, 8, stream);
  k_conv1<<<dim3(1024), dim3(512), 0, stream>>>(poses, c1w, c1b, bn1g, bn1b,
                                                y1, p1, sc, cnt);
  k_conv2<<<dim3(512), dim3(256), 0, stream>>>(y1, sc, c2w, c2b, bn2g, bn2b,
                                               y2, p2, sc, cnt + 1);
  k_gru_pipe<<<dim3(256), dim3(1024), 0, stream>>>(y2, sc, c3w, c3b,
                                                   g0wih, gwih, gwhh, gbih, gbhh,
                                                   ow, ob, o2w, o2b, outv);
}

// Round 18
// 108.447 us; speedup vs baseline: 2.8559x; 2.8559x over previous
//
#include <hip/hip_runtime.h>

typedef unsigned short u16;
typedef __attribute__((ext_vector_type(8))) short bf16x8;
typedef __attribute__((ext_vector_type(4))) short bf16x4;
typedef __attribute__((ext_vector_type(4))) float f32x4;

#define TP 28
#define NB 4096
#define L2E 1.4426950408889634f

__device__ __forceinline__ u16 f2bf(float x) {
  union { float f; unsigned u; } v; v.f = x;
  unsigned u = v.u;
  return (u16)((u + 0x7fffu + ((u >> 16) & 1u)) >> 16);
}
__device__ __forceinline__ float rcp_(float x) {
  float r;
  asm("v_rcp_f32 %0, %1" : "=v"(r) : "v"(x));
  return r;
}
__device__ __forceinline__ float exp2_(float x) {
  float r;
  asm("v_exp_f32 %0, %1" : "=v"(r) : "v"(x));
  return r;
}
__device__ __forceinline__ float sigm2(float x) { return rcp_(1.0f + exp2_(-x)); }
__device__ __forceinline__ float tanh2(float x) { return 1.0f - 2.0f * rcp_(1.0f + exp2_(x)); }
__device__ __forceinline__ float sigm(float x) { return rcp_(1.0f + __expf(-x)); }
__device__ __forceinline__ float leaky(float x) { return x >= 0.0f ? x : 0.1f * x; }
__device__ __forceinline__ f32x4 mfma16(bf16x8 a, bf16x8 b, f32x4 c) {
  return __builtin_amdgcn_mfma_f32_16x16x32_bf16(a, b, c, 0, 0, 0);
}
__device__ __forceinline__ bf16x8 pack8s(float4 a, float4 b, float s) {
  bf16x8 f;
  f[0] = (short)f2bf(a.x * s); f[1] = (short)f2bf(a.y * s);
  f[2] = (short)f2bf(a.z * s); f[3] = (short)f2bf(a.w * s);
  f[4] = (short)f2bf(b.x * s); f[5] = (short)f2bf(b.y * s);
  f[6] = (short)f2bf(b.z * s); f[7] = (short)f2bf(b.w * s);
  return f;
}
__device__ __forceinline__ bf16x8 ldfrag8s(const float* p, float s) {
  float4 u0 = *(const float4*)p;
  float4 u1 = *(const float4*)(p + 4);
  return pack8s(u0, u1, s);
}

// ---------------- conv1: wave-independent staging + compute (R16 proven) ----------------
__global__ __launch_bounds__(512, 4) void k_conv1(
    const float* __restrict__ poses, const float* __restrict__ w1,
    const float* __restrict__ b1, float* __restrict__ y1,
    float* __restrict__ p1)
{
  __shared__ __align__(16) u16 xw[8][3264];   // per-wave window (3240 + pad)
  __shared__ __align__(16) u16 wt[16][544];   // [co][k], k = tap*180+ci; k>=540 zero
  __shared__ float sp[8][16];
  __shared__ float sq[8][16];
  const int tid = threadIdx.x;
  const int lane = tid & 63;
  const int wv = tid >> 6;

  if (tid < 64) wt[tid >> 2][540 + (tid & 3)] = 0;
  for (int i = tid; i < 8640; i += 512) {
    int co_ = i / 540, r = i % 540, ci = r / 3, tap = r % 3;
    wt[co_][tap * 180 + ci] = f2bf(w1[i]);
  }
  __syncthreads();

  const int b0 = blockIdx.x * 4;
  const int bb = wv >> 1;
  const int b = b0 + bb;
  const int t0 = (wv & 1) * 16;
  {
    const float4* src = (const float4*)(poses + (size_t)b * 6120 + t0 * 180);
    u16* dst = xw[wv];
    if (lane < 24) dst[3240 + lane] = 0;
#pragma unroll
    for (int j = 0; j < 13; ++j) {
      const int idx = j * 64 + lane;
      if (idx < 810) {
        float4 v = src[idx];
        unsigned lo = (unsigned)f2bf(v.x) | ((unsigned)f2bf(v.y) << 16);
        unsigned hi = (unsigned)f2bf(v.z) | ((unsigned)f2bf(v.w) << 16);
        *(uint2*)&dst[idx * 4] = make_uint2(lo, hi);
      }
    }
  }
  // no block barrier: each wave reads only its own region (lgkmcnt-ordered)

  const int co = lane & 15;
  const int kgrp = lane >> 4;
  const int kg = kgrp * 8;
  const int R0 = kgrp * 4;
  const u16* pr = &xw[wv][co * 180];
  const float bias = b1[co];
  f32x4 acc = {bias, bias, bias, bias};

#pragma unroll
  for (int s = 0; s < 17; ++s) {
    bf16x4 lo = *(const bf16x4*)(pr + s * 32 + kg);
    bf16x4 hi = *(const bf16x4*)(pr + s * 32 + kg + 4);
    bf16x8 a0 = {lo[0], lo[1], lo[2], lo[3], hi[0], hi[1], hi[2], hi[3]};
    bf16x8 wf = *(const bf16x8*)&wt[co][s * 32 + kg];
    acc = mfma16(a0, wf, acc);
  }

  float s_ = 0.f, q_ = 0.f;
#pragma unroll
  for (int r = 0; r < 4; ++r) { s_ += acc[r]; q_ += acc[r] * acc[r]; }
  *(float4*)(y1 + (size_t)b * 512 + co * 32 + t0 + R0) =
      make_float4(acc[0], acc[1], acc[2], acc[3]);
  s_ += __shfl_xor(s_, 16); q_ += __shfl_xor(q_, 16);
  s_ += __shfl_xor(s_, 32); q_ += __shfl_xor(q_, 32);
  if (lane < 16) { sp[wv][co] = s_; sq[wv][co] = q_; }
  __syncthreads();
  if (tid < 32) {
    int ss = tid >> 4, c = tid & 15;
    float v = 0.f;
#pragma unroll
    for (int w2 = 0; w2 < 8; ++w2) v += ss ? sq[w2][c] : sp[w2][c];
    p1[blockIdx.x * 32 + ss * 16 + c] = v;
  }
}

// p1: [1024][32] -> per-channel scale/shift
__global__ __launch_bounds__(1024) void k_stats1(
    const float* __restrict__ p1, const float* __restrict__ g,
    const float* __restrict__ bb, float* __restrict__ sc)
{
  __shared__ float red[32][32];
  __shared__ float tot[32];
  const int tid = threadIdx.x;
  const int col = tid & 31, rg = tid >> 5;
  float a = 0;
  for (int r = rg; r < 1024; r += 32) a += p1[r * 32 + col];
  red[rg][col] = a;
  __syncthreads();
  if (tid < 32) {
    float t = 0;
    for (int i = 0; i < 32; ++i) t += red[i][tid];
    tot[tid] = t;
  }
  __syncthreads();
  if (tid < 16) {
    const float inv = 1.0f / 131072.0f;
    float m = tot[tid] * inv;
    float var = tot[16 + tid] * inv - m * m;
    float s = g[tid] * rsqrtf(fmaxf(var, 0.0f) + 1e-5f);
    sc[tid] = s;
    sc[16 + tid] = bb[tid] - m * s;
  }
}

// -------- conv2: bn1+leaky(y1) -> y2 [B,8,30] + BN2 partials --------
__global__ __launch_bounds__(256) void k_conv2(
    const float* __restrict__ y1, const float* __restrict__ sc,
    const float* __restrict__ w2, const float* __restrict__ b2,
    float* __restrict__ y2, float* __restrict__ p2)
{
  __shared__ float a1[8][16][33];
  __shared__ float w2s[384];
  __shared__ float sp[4][8][2];
  const int tid = threadIdx.x;
  const int b0 = blockIdx.x * 8;
  for (int i = tid; i < 384; i += 256) w2s[i] = w2[i];
  for (int i = tid; i < 4096; i += 256) {
    int bb = i >> 9, c = (i >> 5) & 15, t = i & 31;
    float v = y1[(size_t)(b0 + bb) * 512 + c * 32 + t] * sc[c] + sc[16 + c];
    a1[bb][c][t] = leaky(v);
  }
  __syncthreads();
  float acc[8];
  const int bb = tid / 30, t = tid % 30;
  const bool act = tid < 240;
#pragma unroll
  for (int co = 0; co < 8; ++co) acc[co] = act ? b2[co] : 0.0f;
  if (act) {
    for (int ci = 0; ci < 16; ++ci) {
      float x0 = a1[bb][ci][t], x1 = a1[bb][ci][t + 1], x2 = a1[bb][ci][t + 2];
#pragma unroll
      for (int co = 0; co < 8; ++co) {
        const float* wp = &w2s[co * 48 + ci * 3];
        acc[co] += x0 * wp[0] + x1 * wp[1] + x2 * wp[2];
      }
    }
    for (int co = 0; co < 8; ++co)
      y2[(size_t)(b0 + bb) * 240 + co * 30 + t] = acc[co];
  }
  const int w = tid >> 6;
#pragma unroll
  for (int co = 0; co < 8; ++co) {
    float s = act ? acc[co] : 0.0f;
    float q = s * s;
#pragma unroll
    for (int m = 1; m <= 32; m <<= 1) { s += __shfl_xor(s, m); q += __shfl_xor(q, m); }
    if ((tid & 63) == 0) { sp[w][co][0] = s; sp[w][co][1] = q; }
  }
  __syncthreads();
  if (tid < 16) {
    int s = tid >> 3, c = tid & 7;
    p2[blockIdx.x * 16 + s * 8 + c] = sp[0][c][s] + sp[1][c][s] + sp[2][c][s] + sp[3][c][s];
  }
}

__global__ __launch_bounds__(256) void k_stats2(
    const float* __restrict__ p2, const float* __restrict__ g,
    const float* __restrict__ bb, float* __restrict__ sc)
{
  __shared__ float red[16][16];
  __shared__ float tot[16];
  const int tid = threadIdx.x;
  const int col = tid & 15, r0 = tid >> 4;
  float a = 0;
  for (int r = r0; r < 512; r += 16) a += p2[r * 16 + col];
  red[r0][col] = a;
  __syncthreads();
  if (tid < 16) {
    float t = 0;
    for (int i = 0; i < 16; ++i) t += red[i][tid];
    tot[tid] = t;
  }
  __syncthreads();
  if (tid < 8) {
    const float inv = 1.0f / 122880.0f;
    float m = tot[tid] * inv;
    float var = tot[8 + tid] * inv - m * m;
    float s = g[tid] * rsqrtf(fmaxf(var, 0.0f) + 1e-5f);
    sc[32 + tid] = s;
    sc[40 + tid] = bb[tid] - m * s;
  }
}

// -------- gru: conv3 prologue (per-block 16 batches -> LDS featl) + 4-layer pipe + head --------
__global__ __launch_bounds__(1024) void k_gru_pipe(
    const float* __restrict__ y2, const float* __restrict__ sc,
    const float* __restrict__ w3, const float* __restrict__ b3,
    const float* __restrict__ g0wih,   // [192][8]
    const float* __restrict__ gwih,    // [3][192][64]
    const float* __restrict__ gwhh,    // [4][192][64]
    const float* __restrict__ gbih,    // [4][192]
    const float* __restrict__ gbhh,    // [4][192]
    const float* __restrict__ ow, const float* __restrict__ ob,
    const float* __restrict__ o2w, const float* __restrict__ o2b,
    float* __restrict__ out)
{
  __shared__ __align__(16) u16 featl[TP][16][40];  // cols 8..39 zero (K padding)
  __shared__ __align__(16) u16 hl[4][2][16][72];
  __shared__ float a2[16][8][31];
  __shared__ float w3s[192];
  __shared__ float sph[4][16];
  const int tid = threadIdx.x;
  const int b0 = blockIdx.x * 16;
  const int lane = tid & 63;
  const int wv = tid >> 6;        // 0..15
  const int l = wv >> 2;          // layer 0..3
  const int c = wv & 3;           // col-group 0..3
  const int row = lane & 15;
  const int kgrp = lane >> 4;
  const int kg = kgrp * 8;
  const int R0 = kgrp * 4;
  const int cr = c * 16 + row;    // gate column 0..63

  // prologue stage A: zero hl+featl, load w3s, stage bn2+leaky(y2) into a2
  for (int i = tid; i < 4 * 2 * 16 * 72; i += 1024) ((u16*)hl)[i] = 0;
  for (int i = tid; i < TP * 16 * 40; i += 1024) ((u16*)featl)[i] = 0;
  for (int i = tid; i < 192; i += 1024) w3s[i] = w3[i];
  for (int i = tid; i < 3840; i += 1024) {
    int bb = i / 240, rem = i % 240, cc = rem / 30, tt = rem % 30;
    float v = y2[(size_t)(b0 + bb) * 240 + cc * 30 + tt] * sc[32 + cc] + sc[40 + cc];
    a2[bb][cc][tt] = leaky(v);
  }

  // weight fragments (registers, independent of LDS)
  bf16x8 Wx[3][2], Wh[3][2];
  if (l == 0) {
#pragma unroll
    for (int g = 0; g < 3; ++g) {
      const float sc_ = (g == 2) ? 2.f * L2E : L2E;
      bf16x8 z;
#pragma unroll
      for (int j = 0; j < 8; ++j) z[j] = 0;
      if (kg == 0) z = ldfrag8s(g0wih + (g * 64 + cr) * 8, sc_);
      Wx[g][0] = z;
      Wx[g][1] = z;
    }
  } else {
#pragma unroll
    for (int g = 0; g < 3; ++g) {
      const float sc_ = (g == 2) ? 2.f * L2E : L2E;
#pragma unroll
      for (int s = 0; s < 2; ++s)
        Wx[g][s] = ldfrag8s(gwih + (l - 1) * 12288 + (g * 64 + cr) * 64 + s * 32 + kg, sc_);
    }
  }
#pragma unroll
  for (int g = 0; g < 3; ++g) {
    const float sc_ = (g == 2) ? 2.f * L2E : L2E;
#pragma unroll
    for (int s = 0; s < 2; ++s)
      Wh[g][s] = ldfrag8s(gwhh + l * 12288 + (g * 64 + cr) * 64 + s * 32 + kg, sc_);
  }

  const float br = (gbih[l * 192 + cr] + gbhh[l * 192 + cr]) * L2E;
  const float bz = (gbih[l * 192 + 64 + cr] + gbhh[l * 192 + 64 + cr]) * L2E;
  const float bi = gbih[l * 192 + 128 + cr] * 2.f * L2E;
  const float bh = gbhh[l * 192 + 128 + cr] * 2.f * L2E;

  __syncthreads();   // stage A complete (zeros + a2)

  // prologue stage B: conv3 -> featl cols 0..7
  if (tid < 448) {
    int bb = tid / 28, t = tid % 28;
    float accc[8];
#pragma unroll
    for (int co = 0; co < 8; ++co) accc[co] = b3[co];
    for (int ci = 0; ci < 8; ++ci) {
      float x0 = a2[bb][ci][t], x1 = a2[bb][ci][t + 1], x2 = a2[bb][ci][t + 2];
#pragma unroll
      for (int co = 0; co < 8; ++co) {
        const float* wp = &w3s[co * 24 + ci * 3];
        accc[co] += x0 * wp[0] + x1 * wp[1] + x2 * wp[2];
      }
    }
    union { u16 h[8]; uint4 v; } u;
#pragma unroll
    for (int co = 0; co < 8; ++co) u.h[co] = f2bf(accc[co]);
    *(uint4*)&featl[t][bb][0] = u.v;
  }
  __syncthreads();   // featl ready

  float hold[4] = {0.f, 0.f, 0.f, 0.f};
  float accL[4] = {0.f, 0.f, 0.f, 0.f};
  const float owv = ow[cr];

  for (int tick = 0; tick < TP + 3; ++tick) {
    const int t = tick - l;
    if (t >= 0 && t < TP) {
      const int cur = t & 1, nxt = cur ^ 1;
      bf16x8 ax0, ax1, ah0, ah1;
      if (l == 0) {
        ax0 = *(const bf16x8*)&featl[t][row][kg];
      } else {
        ax0 = *(const bf16x8*)&hl[l - 1][nxt][row][kg];      // h_{l-1}[t]
        ax1 = *(const bf16x8*)&hl[l - 1][nxt][row][32 + kg];
      }
      ah0 = *(const bf16x8*)&hl[l][cur][row][kg];            // h_l[t-1]
      ah1 = *(const bf16x8*)&hl[l][cur][row][32 + kg];

      f32x4 ar = {br, br, br, br};
      f32x4 az = {bz, bz, bz, bz};
      f32x4 ai = {bi, bi, bi, bi};
      f32x4 an = {bh, bh, bh, bh};

      __builtin_amdgcn_s_setprio(1);
      ar = mfma16(ax0, Wx[0][0], ar);
      az = mfma16(ax0, Wx[1][0], az);
      ai = mfma16(ax0, Wx[2][0], ai);
      if (l != 0) {
        ar = mfma16(ax1, Wx[0][1], ar);
        az = mfma16(ax1, Wx[1][1], az);
        ai = mfma16(ax1, Wx[2][1], ai);
      }
      ar = mfma16(ah0, Wh[0][0], ar);
      ar = mfma16(ah1, Wh[0][1], ar);
      az = mfma16(ah0, Wh[1][0], az);
      az = mfma16(ah1, Wh[1][1], az);
      an = mfma16(ah0, Wh[2][0], an);
      an = mfma16(ah1, Wh[2][1], an);
      __builtin_amdgcn_s_setprio(0);

      float o2 = 0.f;
      if (l == 3) o2 = o2w[t];
      u16 hb[4];
#pragma unroll
      for (int r = 0; r < 4; ++r) {
        float rr = sigm2(ar[r]);
        float zz = sigm2(az[r]);
        float nn = tanh2(ai[r] + rr * an[r]);
        float hv = nn + zz * (hold[r] - nn);
        hold[r] = hv;
        hb[r] = f2bf(hv);
        if (l == 3) accL[r] += hv * owv * o2;
      }
#pragma unroll
      for (int r = 0; r < 4; ++r) hl[l][nxt][R0 + r][cr] = hb[r];
    }
    __syncthreads();
  }

  if (l == 3) {
#pragma unroll
    for (int r = 0; r < 4; ++r) {
      accL[r] += __shfl_xor(accL[r], 1);
      accL[r] += __shfl_xor(accL[r], 2);
      accL[r] += __shfl_xor(accL[r], 4);
      accL[r] += __shfl_xor(accL[r], 8);
    }
    if ((lane & 15) == 0) {
#pragma unroll
      for (int r = 0; r < 4; ++r) sph[c][R0 + r] = accL[r];
    }
  }
  __syncthreads();
  if (tid < 16) {
    float s = sph[0][tid] + sph[1][tid] + sph[2][tid] + sph[3][tid];
    float so2 = 0.f;
    for (int t = 0; t < TP; ++t) so2 += o2w[t];
    out[b0 + tid] = sigm(s + ob[0] * so2 + o2b[0]);
  }
}

extern "C" void kernel_launch(void* const* d_in, const int* in_sizes, int n_in,
                              void* d_out, int out_size, void* d_ws, size_t ws_size,
                              hipStream_t stream)
{
  const float* poses = (const float*)d_in[0];
  const float* c1w = (const float*)d_in[1];
  const float* c1b = (const float*)d_in[2];
  const float* bn1g = (const float*)d_in[3];
  const float* bn1b = (const float*)d_in[4];
  const float* c2w = (const float*)d_in[5];
  const float* c2b = (const float*)d_in[6];
  const float* bn2g = (const float*)d_in[7];
  const float* bn2b = (const float*)d_in[8];
  const float* c3w = (const float*)d_in[9];
  const float* c3b = (const float*)d_in[10];
  const float* g0wih = (const float*)d_in[11];  // [192][8]
  const float* gwih = (const float*)d_in[12];   // [3][192][64]
  const float* gwhh = (const float*)d_in[13];   // [4][192][64]
  const float* gbih = (const float*)d_in[14];   // [4][192]
  const float* gbhh = (const float*)d_in[15];   // [4][192]
  const float* ow = (const float*)d_in[16];
  const float* ob = (const float*)d_in[17];
  const float* o2w = (const float*)d_in[18];
  const float* o2b = (const float*)d_in[19];

  float* ws = (float*)d_ws;
  float* y1 = ws;                         // 2,097,152 f32
  float* y2 = ws + 2097152;               //   983,040 f32
  float* p1 = ws + 3080192;               //    32,768 f32 (1024 x 32)
  float* p2 = ws + 3112960;               //     8,192 f32 (512 x 16)
  float* sc = ws + 3121152;               //        48 f32
  float* outv = (float*)d_out;

  k_conv1<<<dim3(1024), dim3(512), 0, stream>>>(poses, c1w, c1b, y1, p1);
  k_stats1<<<dim3(1), dim3(1024), 0, stream>>>(p1, bn1g, bn1b, sc);
  k_conv2<<<dim3(512), dim3(256), 0, stream>>>(y1, sc, c2w, c2b, y2, p2);
  k_stats2<<<dim3(1), dim3(256), 0, stream>>>(p2, bn2g, bn2b, sc);
  k_gru_pipe<<<dim3(256), dim3(1024), 0, stream>>>(y2, sc, c3w, c3b,
                                                   g0wih, gwih, gwhh, gbih, gbhh,
                                                   ow, ob, o2w, o2b, outv);
}

// Round 19
// 105.063 us; speedup vs baseline: 2.9479x; 1.0322x over previous
//
#include <hip/hip_runtime.h>

typedef unsigned short u16;
typedef __attribute__((ext_vector_type(8))) short bf16x8;
typedef __attribute__((ext_vector_type(4))) short bf16x4;
typedef __attribute__((ext_vector_type(4))) float f32x4;

#define TP 28
#define NB 4096
#define L2E 1.4426950408889634f

__device__ __forceinline__ u16 f2bf(float x) {
  union { float f; unsigned u; } v; v.f = x;
  unsigned u = v.u;
  return (u16)((u + 0x7fffu + ((u >> 16) & 1u)) >> 16);
}
__device__ __forceinline__ unsigned cvtpk(float lo, float hi) {
  unsigned r;
  asm("v_cvt_pk_bf16_f32 %0, %1, %2" : "=v"(r) : "v"(lo), "v"(hi));
  return r;
}
__device__ __forceinline__ float rcp_(float x) {
  float r;
  asm("v_rcp_f32 %0, %1" : "=v"(r) : "v"(x));
  return r;
}
__device__ __forceinline__ float exp2_(float x) {
  float r;
  asm("v_exp_f32 %0, %1" : "=v"(r) : "v"(x));
  return r;
}
__device__ __forceinline__ float sigm2(float x) { return rcp_(1.0f + exp2_(-x)); }
__device__ __forceinline__ float tanh2(float x) { return 1.0f - 2.0f * rcp_(1.0f + exp2_(x)); }
__device__ __forceinline__ float sigm(float x) { return rcp_(1.0f + __expf(-x)); }
__device__ __forceinline__ float leaky(float x) { return x >= 0.0f ? x : 0.1f * x; }
__device__ __forceinline__ f32x4 mfma16(bf16x8 a, bf16x8 b, f32x4 c) {
  return __builtin_amdgcn_mfma_f32_16x16x32_bf16(a, b, c, 0, 0, 0);
}
__device__ __forceinline__ bf16x8 pack8s(float4 a, float4 b, float s) {
  bf16x8 f;
  f[0] = (short)f2bf(a.x * s); f[1] = (short)f2bf(a.y * s);
  f[2] = (short)f2bf(a.z * s); f[3] = (short)f2bf(a.w * s);
  f[4] = (short)f2bf(b.x * s); f[5] = (short)f2bf(b.y * s);
  f[6] = (short)f2bf(b.z * s); f[7] = (short)f2bf(b.w * s);
  return f;
}
__device__ __forceinline__ bf16x8 ldfrag8s(const float* p, float s) {
  float4 u0 = *(const float4*)p;
  float4 u1 = *(const float4*)(p + 4);
  return pack8s(u0, u1, s);
}

// ---------------- conv1: wave-independent staging + compute ----------------
__global__ __launch_bounds__(512, 4) void k_conv1(
    const float* __restrict__ poses, const float* __restrict__ w1,
    const float* __restrict__ b1, float* __restrict__ y1,
    float* __restrict__ p1)
{
  __shared__ __align__(16) u16 xw[8][3264];   // per-wave window (3240 + pad)
  __shared__ __align__(16) u16 wt[16][544];   // [co][k], k = tap*180+ci; k>=540 zero
  __shared__ float sp[8][16];
  __shared__ float sq[8][16];
  const int tid = threadIdx.x;
  const int lane = tid & 63;
  const int wv = tid >> 6;

  if (tid < 64) wt[tid >> 2][540 + (tid & 3)] = 0;
  for (int i = tid; i < 8640; i += 512) {
    int co_ = i / 540, r = i % 540, ci = r / 3, tap = r % 3;
    wt[co_][tap * 180 + ci] = f2bf(w1[i]);
  }
  __syncthreads();

  const int b0 = blockIdx.x * 4;
  const int bb = wv >> 1;
  const int b = b0 + bb;
  const int t0 = (wv & 1) * 16;
  {
    const float4* src = (const float4*)(poses + (size_t)b * 6120 + t0 * 180);
    u16* dst = xw[wv];
    if (lane < 24) dst[3240 + lane] = 0;
#pragma unroll
    for (int j = 0; j < 13; ++j) {
      const int idx = j * 64 + lane;
      if (idx < 810) {
        float4 v = src[idx];
        unsigned lo = cvtpk(v.x, v.y);
        unsigned hi = cvtpk(v.z, v.w);
        *(uint2*)&dst[idx * 4] = make_uint2(lo, hi);
      }
    }
  }
  // no block barrier: each wave reads only its own region (lgkmcnt-ordered)

  const int co = lane & 15;
  const int kgrp = lane >> 4;
  const int kg = kgrp * 8;
  const int R0 = kgrp * 4;
  const u16* pr = &xw[wv][co * 180];
  const float bias = b1[co];
  f32x4 acc = {bias, bias, bias, bias};

#pragma unroll
  for (int s = 0; s < 17; ++s) {
    bf16x4 lo = *(const bf16x4*)(pr + s * 32 + kg);
    bf16x4 hi = *(const bf16x4*)(pr + s * 32 + kg + 4);
    bf16x8 a0 = {lo[0], lo[1], lo[2], lo[3], hi[0], hi[1], hi[2], hi[3]};
    bf16x8 wf = *(const bf16x8*)&wt[co][s * 32 + kg];
    acc = mfma16(a0, wf, acc);
  }

  float s_ = 0.f, q_ = 0.f;
#pragma unroll
  for (int r = 0; r < 4; ++r) { s_ += acc[r]; q_ += acc[r] * acc[r]; }
  *(float4*)(y1 + (size_t)b * 512 + co * 32 + t0 + R0) =
      make_float4(acc[0], acc[1], acc[2], acc[3]);
  s_ += __shfl_xor(s_, 16); q_ += __shfl_xor(q_, 16);
  s_ += __shfl_xor(s_, 32); q_ += __shfl_xor(q_, 32);
  if (lane < 16) { sp[wv][co] = s_; sq[wv][co] = q_; }
  __syncthreads();
  if (tid < 32) {
    int ss = tid >> 4, c = tid & 15;
    float v = 0.f;
#pragma unroll
    for (int w2 = 0; w2 < 8; ++w2) v += ss ? sq[w2][c] : sp[w2][c];
    p1[blockIdx.x * 32 + ss * 16 + c] = v;
  }
}

// p1: [1024][32] -> per-channel scale/shift
__global__ __launch_bounds__(1024) void k_stats1(
    const float* __restrict__ p1, const float* __restrict__ g,
    const float* __restrict__ bb, float* __restrict__ sc)
{
  __shared__ float red[32][32];
  __shared__ float tot[32];
  const int tid = threadIdx.x;
  const int col = tid & 31, rg = tid >> 5;
  float a = 0;
  for (int r = rg; r < 1024; r += 32) a += p1[r * 32 + col];
  red[rg][col] = a;
  __syncthreads();
  if (tid < 32) {
    float t = 0;
    for (int i = 0; i < 32; ++i) t += red[i][tid];
    tot[tid] = t;
  }
  __syncthreads();
  if (tid < 16) {
    const float inv = 1.0f / 131072.0f;
    float m = tot[tid] * inv;
    float var = tot[16 + tid] * inv - m * m;
    float s = g[tid] * rsqrtf(fmaxf(var, 0.0f) + 1e-5f);
    sc[tid] = s;
    sc[16 + tid] = bb[tid] - m * s;
  }
}

// -------- conv2: bn1+leaky(y1) -> y2 [B,8,30] + BN2 partials --------
__global__ __launch_bounds__(256) void k_conv2(
    const float* __restrict__ y1, const float* __restrict__ sc,
    const float* __restrict__ w2, const float* __restrict__ b2,
    float* __restrict__ y2, float* __restrict__ p2)
{
  __shared__ float a1[8][16][33];
  __shared__ float w2s[384];
  __shared__ float sp[4][8][2];
  const int tid = threadIdx.x;
  const int b0 = blockIdx.x * 8;
  for (int i = tid; i < 384; i += 256) w2s[i] = w2[i];
  for (int i = tid; i < 4096; i += 256) {
    int bb = i >> 9, c = (i >> 5) & 15, t = i & 31;
    float v = y1[(size_t)(b0 + bb) * 512 + c * 32 + t] * sc[c] + sc[16 + c];
    a1[bb][c][t] = leaky(v);
  }
  __syncthreads();
  float acc[8];
  const int bb = tid / 30, t = tid % 30;
  const bool act = tid < 240;
#pragma unroll
  for (int co = 0; co < 8; ++co) acc[co] = act ? b2[co] : 0.0f;
  if (act) {
    for (int ci = 0; ci < 16; ++ci) {
      float x0 = a1[bb][ci][t], x1 = a1[bb][ci][t + 1], x2 = a1[bb][ci][t + 2];
#pragma unroll
      for (int co = 0; co < 8; ++co) {
        const float* wp = &w2s[co * 48 + ci * 3];
        acc[co] += x0 * wp[0] + x1 * wp[1] + x2 * wp[2];
      }
    }
    for (int co = 0; co < 8; ++co)
      y2[(size_t)(b0 + bb) * 240 + co * 30 + t] = acc[co];
  }
  const int w = tid >> 6;
#pragma unroll
  for (int co = 0; co < 8; ++co) {
    float s = act ? acc[co] : 0.0f;
    float q = s * s;
#pragma unroll
    for (int m = 1; m <= 32; m <<= 1) { s += __shfl_xor(s, m); q += __shfl_xor(q, m); }
    if ((tid & 63) == 0) { sp[w][co][0] = s; sp[w][co][1] = q; }
  }
  __syncthreads();
  if (tid < 16) {
    int s = tid >> 3, c = tid & 7;
    p2[blockIdx.x * 16 + s * 8 + c] = sp[0][c][s] + sp[1][c][s] + sp[2][c][s] + sp[3][c][s];
  }
}

__global__ __launch_bounds__(256) void k_stats2(
    const float* __restrict__ p2, const float* __restrict__ g,
    const float* __restrict__ bb, float* __restrict__ sc)
{
  __shared__ float red[16][16];
  __shared__ float tot[16];
  const int tid = threadIdx.x;
  const int col = tid & 15, r0 = tid >> 4;
  float a = 0;
  for (int r = r0; r < 512; r += 16) a += p2[r * 16 + col];
  red[r0][col] = a;
  __syncthreads();
  if (tid < 16) {
    float t = 0;
    for (int i = 0; i < 16; ++i) t += red[i][tid];
    tot[tid] = t;
  }
  __syncthreads();
  if (tid < 8) {
    const float inv = 1.0f / 122880.0f;
    float m = tot[tid] * inv;
    float var = tot[8 + tid] * inv - m * m;
    float s = g[tid] * rsqrtf(fmaxf(var, 0.0f) + 1e-5f);
    sc[32 + tid] = s;
    sc[40 + tid] = bb[tid] - m * s;
  }
}

// -------- gru: conv3 prologue + 4-layer pipe + head (no setprio, cvt_pk pack) --------
__global__ __launch_bounds__(1024) void k_gru_pipe(
    const float* __restrict__ y2, const float* __restrict__ sc,
    const float* __restrict__ w3, const float* __restrict__ b3,
    const float* __restrict__ g0wih,   // [192][8]
    const float* __restrict__ gwih,    // [3][192][64]
    const float* __restrict__ gwhh,    // [4][192][64]
    const float* __restrict__ gbih,    // [4][192]
    const float* __restrict__ gbhh,    // [4][192]
    const float* __restrict__ ow, const float* __restrict__ ob,
    const float* __restrict__ o2w, const float* __restrict__ o2b,
    float* __restrict__ out)
{
  __shared__ __align__(16) u16 featl[TP][16][40];  // cols 8..39 zero (K padding)
  __shared__ __align__(16) u16 hl[4][2][16][72];
  __shared__ float a2[16][8][31];
  __shared__ float w3s[192];
  __shared__ float sph[4][16];
  const int tid = threadIdx.x;
  const int b0 = blockIdx.x * 16;
  const int lane = tid & 63;
  const int wv = tid >> 6;        // 0..15
  const int l = wv >> 2;          // layer 0..3
  const int c = wv & 3;           // col-group 0..3
  const int row = lane & 15;
  const int kgrp = lane >> 4;
  const int kg = kgrp * 8;
  const int R0 = kgrp * 4;
  const int cr = c * 16 + row;    // gate column 0..63

  // prologue stage A: zero hl+featl, load w3s, stage bn2+leaky(y2) into a2
  for (int i = tid; i < 4 * 2 * 16 * 72; i += 1024) ((u16*)hl)[i] = 0;
  for (int i = tid; i < TP * 16 * 40; i += 1024) ((u16*)featl)[i] = 0;
  for (int i = tid; i < 192; i += 1024) w3s[i] = w3[i];
  for (int i = tid; i < 3840; i += 1024) {
    int bb = i / 240, rem = i % 240, cc = rem / 30, tt = rem % 30;
    float v = y2[(size_t)(b0 + bb) * 240 + cc * 30 + tt] * sc[32 + cc] + sc[40 + cc];
    a2[bb][cc][tt] = leaky(v);
  }

  // weight fragments (registers, independent of LDS)
  bf16x8 Wx[3][2], Wh[3][2];
  if (l == 0) {
#pragma unroll
    for (int g = 0; g < 3; ++g) {
      const float sc_ = (g == 2) ? 2.f * L2E : L2E;
      bf16x8 z;
#pragma unroll
      for (int j = 0; j < 8; ++j) z[j] = 0;
      if (kg == 0) z = ldfrag8s(g0wih + (g * 64 + cr) * 8, sc_);
      Wx[g][0] = z;
      Wx[g][1] = z;
    }
  } else {
#pragma unroll
    for (int g = 0; g < 3; ++g) {
      const float sc_ = (g == 2) ? 2.f * L2E : L2E;
#pragma unroll
      for (int s = 0; s < 2; ++s)
        Wx[g][s] = ldfrag8s(gwih + (l - 1) * 12288 + (g * 64 + cr) * 64 + s * 32 + kg, sc_);
    }
  }
#pragma unroll
  for (int g = 0; g < 3; ++g) {
    const float sc_ = (g == 2) ? 2.f * L2E : L2E;
#pragma unroll
    for (int s = 0; s < 2; ++s)
      Wh[g][s] = ldfrag8s(gwhh + l * 12288 + (g * 64 + cr) * 64 + s * 32 + kg, sc_);
  }

  const float br = (gbih[l * 192 + cr] + gbhh[l * 192 + cr]) * L2E;
  const float bz = (gbih[l * 192 + 64 + cr] + gbhh[l * 192 + 64 + cr]) * L2E;
  const float bi = gbih[l * 192 + 128 + cr] * 2.f * L2E;
  const float bh = gbhh[l * 192 + 128 + cr] * 2.f * L2E;

  __syncthreads();   // stage A complete (zeros + a2)

  // prologue stage B: conv3 -> featl cols 0..7
  if (tid < 448) {
    int bb = tid / 28, t = tid % 28;
    float accc[8];
#pragma unroll
    for (int co = 0; co < 8; ++co) accc[co] = b3[co];
    for (int ci = 0; ci < 8; ++ci) {
      float x0 = a2[bb][ci][t], x1 = a2[bb][ci][t + 1], x2 = a2[bb][ci][t + 2];
#pragma unroll
      for (int co = 0; co < 8; ++co) {
        const float* wp = &w3s[co * 24 + ci * 3];
        accc[co] += x0 * wp[0] + x1 * wp[1] + x2 * wp[2];
      }
    }
    uint4 u;
    u.x = cvtpk(accc[0], accc[1]);
    u.y = cvtpk(accc[2], accc[3]);
    u.z = cvtpk(accc[4], accc[5]);
    u.w = cvtpk(accc[6], accc[7]);
    *(uint4*)&featl[t][bb][0] = u;
  }
  __syncthreads();   // featl ready

  float hold[4] = {0.f, 0.f, 0.f, 0.f};
  float accL[4] = {0.f, 0.f, 0.f, 0.f};
  const float owv = ow[cr];

  for (int tick = 0; tick < TP + 3; ++tick) {
    const int t = tick - l;
    if (t >= 0 && t < TP) {
      const int cur = t & 1, nxt = cur ^ 1;
      bf16x8 ax0, ax1, ah0, ah1;
      if (l == 0) {
        ax0 = *(const bf16x8*)&featl[t][row][kg];
      } else {
        ax0 = *(const bf16x8*)&hl[l - 1][nxt][row][kg];      // h_{l-1}[t]
        ax1 = *(const bf16x8*)&hl[l - 1][nxt][row][32 + kg];
      }
      ah0 = *(const bf16x8*)&hl[l][cur][row][kg];            // h_l[t-1]
      ah1 = *(const bf16x8*)&hl[l][cur][row][32 + kg];

      f32x4 ar = {br, br, br, br};
      f32x4 az = {bz, bz, bz, bz};
      f32x4 ai = {bi, bi, bi, bi};
      f32x4 an = {bh, bh, bh, bh};

      ar = mfma16(ax0, Wx[0][0], ar);
      az = mfma16(ax0, Wx[1][0], az);
      ai = mfma16(ax0, Wx[2][0], ai);
      if (l != 0) {
        ar = mfma16(ax1, Wx[0][1], ar);
        az = mfma16(ax1, Wx[1][1], az);
        ai = mfma16(ax1, Wx[2][1], ai);
      }
      ar = mfma16(ah0, Wh[0][0], ar);
      ar = mfma16(ah1, Wh[0][1], ar);
      az = mfma16(ah0, Wh[1][0], az);
      az = mfma16(ah1, Wh[1][1], az);
      an = mfma16(ah0, Wh[2][0], an);
      an = mfma16(ah1, Wh[2][1], an);

      float o2 = 0.f;
      if (l == 3) o2 = o2w[t];
      float hv_[4];
#pragma unroll
      for (int r = 0; r < 4; ++r) {
        float rr = sigm2(ar[r]);
        float zz = sigm2(az[r]);
        float nn = tanh2(ai[r] + rr * an[r]);
        float hv = nn + zz * (hold[r] - nn);
        hold[r] = hv;
        hv_[r] = hv;
        if (l == 3) accL[r] += hv * owv * o2;
      }
      unsigned p01 = cvtpk(hv_[0], hv_[1]);
      unsigned p23 = cvtpk(hv_[2], hv_[3]);
      hl[l][nxt][R0 + 0][cr] = (u16)p01;
      hl[l][nxt][R0 + 1][cr] = (u16)(p01 >> 16);
      hl[l][nxt][R0 + 2][cr] = (u16)p23;
      hl[l][nxt][R0 + 3][cr] = (u16)(p23 >> 16);
    }
    __syncthreads();
  }

  if (l == 3) {
#pragma unroll
    for (int r = 0; r < 4; ++r) {
      accL[r] += __shfl_xor(accL[r], 1);
      accL[r] += __shfl_xor(accL[r], 2);
      accL[r] += __shfl_xor(accL[r], 4);
      accL[r] += __shfl_xor(accL[r], 8);
    }
    if ((lane & 15) == 0) {
#pragma unroll
      for (int r = 0; r < 4; ++r) sph[c][R0 + r] = accL[r];
    }
  }
  __syncthreads();
  if (tid < 16) {
    float s = sph[0][tid] + sph[1][tid] + sph[2][tid] + sph[3][tid];
    float so2 = 0.f;
    for (int t = 0; t < TP; ++t) so2 += o2w[t];
    out[b0 + tid] = sigm(s + ob[0] * so2 + o2b[0]);
  }
}

extern "C" void kernel_launch(void* const* d_in, const int* in_sizes, int n_in,
                              void* d_out, int out_size, void* d_ws, size_t ws_size,
                              hipStream_t stream)
{
  const float* poses = (const float*)d_in[0];
  const float* c1w = (const float*)d_in[1];
  const float* c1b = (const float*)d_in[2];
  const float* bn1g = (const float*)d_in[3];
  const float* bn1b = (const float*)d_in[4];
  const float* c2w = (const float*)d_in[5];
  const float* c2b = (const float*)d_in[6];
  const float* bn2g = (const float*)d_in[7];
  const float* bn2b = (const float*)d_in[8];
  const float* c3w = (const float*)d_in[9];
  const float* c3b = (const float*)d_in[10];
  const float* g0wih = (const float*)d_in[11];  // [192][8]
  const float* gwih = (const float*)d_in[12];   // [3][192][64]
  const float* gwhh = (const float*)d_in[13];   // [4][192][64]
  const float* gbih = (const float*)d_in[14];   // [4][192]
  const float* gbhh = (const float*)d_in[15];   // [4][192]
  const float* ow = (const float*)d_in[16];
  const float* ob = (const float*)d_in[17];
  const float* o2w = (const float*)d_in[18];
  const float* o2b = (const float*)d_in[19];

  float* ws = (float*)d_ws;
  float* y1 = ws;                         // 2,097,152 f32
  float* y2 = ws + 2097152;               //   983,040 f32
  float* p1 = ws + 3080192;               //    32,768 f32 (1024 x 32)
  float* p2 = ws + 3112960;               //     8,192 f32 (512 x 16)
  float* sc = ws + 3121152;               //        48 f32
  float* outv = (float*)d_out;

  k_conv1<<<dim3(1024), dim3(512), 0, stream>>>(poses, c1w, c1b, y1, p1);
  k_stats1<<<dim3(1), dim3(1024), 0, stream>>>(p1, bn1g, bn1b, sc);
  k_conv2<<<dim3(512), dim3(256), 0, stream>>>(y1, sc, c2w, c2b, y2, p2);
  k_stats2<<<dim3(1), dim3(256), 0, stream>>>(p2, bn2g, bn2b, sc);
  k_gru_pipe<<<dim3(256), dim3(1024), 0, stream>>>(y2, sc, c3w, c3b,
                                                   g0wih, gwih, gwhh, gbih, gbhh,
                                                   ow, ob, o2w, o2b, outv);
}